// Round 8
// baseline (145.005 us; speedup 1.0000x reference)
//
#include <hip/hip_runtime.h>

#define T_CNT   128
#define IOU_TH  0.4f
#define K_CONST 2.5f
#define NB_TOT  2048   // 1024 role-A + 1024 role-B, interleaved in groups of 8
#define PPB     256    // priors per chunk (both roles)

// ws layout:
//   [0,32)        double accum[3]: S1=sum(sig), S2=sum(xf), S3=sum(sig*xf*log(bto))
//   [64,1088)     unsigned long long packed[128]: (iou_bits<<32) | ~prior_idx
//   [1152,1156)   unsigned int done counter
//   [4096, +P*4)  float bto[P]
static const size_t WS_ACC_OFF    = 0;
static const size_t WS_PACKED_OFF = 64;
static const size_t WS_DONE_OFF   = 1152;
static const size_t WS_BTO_OFF    = 4096;

// One kernel, two balanced block roles (identical per-block work), plus a
// last-block finalize. Each role uses the layout in which its reduction
// axis needs zero cross-lane work in the hot loop.
__global__ __launch_bounds__(256) void apb_work(
    const float* __restrict__ locs, const float* __restrict__ params,
    const float* __restrict__ truths, float* __restrict__ bto,
    unsigned long long* __restrict__ packed, double* __restrict__ accum,
    unsigned int* __restrict__ done, float* __restrict__ out)
{
    __shared__ float4 s_tb[T_CNT];                    // role A truths
    __shared__ float4 s_p[PPB];                       // role B priors
    __shared__ unsigned long long s_part[4][T_CNT];   // role B partials
    __shared__ float s_red[3][4];
    __shared__ unsigned int s_idx[T_CNT];             // finalize
    __shared__ float s_sw[8];
    __shared__ unsigned int s_ticket;

    const int tid  = threadIdx.x;
    const int lane = tid & 63;
    const int wv   = tid >> 6;
    const int bid  = blockIdx.x;
    const int chunk = (bid >> 4) * 8 + (bid & 7);     // 0..1023 per role
    const bool roleB = (bid >> 3) & 1;
    const int base  = chunk * PPB;

    if (!roleB) {
        // ---- role A: lane = prior (1/thread), broadcast truths from LDS.
        if (tid < T_CNT) s_tb[tid] = ((const float4*)truths)[tid];
        __syncthreads();

        const int p = base + tid;
        float2 c = ((const float2*)locs)[p];
        float w0 = params[3 * p];
        float h0 = params[3 * p + 1];
        const float px1 = c.x - 0.5f * w0, py1 = c.y - 0.5f * h0;
        const float px2 = c.x + 0.5f * w0, py2 = c.y + 0.5f * h0;
        const float parea = (px2 - px1) * (py2 - py1);

        float btmax = 0.f;
#pragma unroll 4
        for (int t = 0; t < T_CNT; ++t) {
            float4 tb = s_tb[t];                       // broadcast, conflict-free
            float ta = (tb.z - tb.x) * (tb.w - tb.y);
            float lx = fmaxf(tb.x, px1);
            float ly = fmaxf(tb.y, py1);
            float rx = fminf(tb.z, px2);
            float ry = fminf(tb.w, py2);
            float w = fmaxf(rx - lx, 0.f);
            float h = fmaxf(ry - ly, 0.f);
            float inter = w * h;
            float iou = inter * __builtin_amdgcn_rcpf((ta + parea) - inter);
            btmax = fmaxf(btmax, iou);
        }

        // epilogue: bto + baseline sums
        bto[p] = btmax;
        float a = params[3 * p + 2];
        float sig = 1.f / (1.f + expf(-a));
        float xf = (btmax > IOU_TH) ? 1.f : 0.f;
        float s1 = sig;
        float s2 = xf;
        float s3 = (xf > 0.f) ? sig * logf(btmax) : 0.f;
#pragma unroll
        for (int off = 32; off; off >>= 1) {
            s1 += __shfl_xor(s1, off, 64);
            s2 += __shfl_xor(s2, off, 64);
            s3 += __shfl_xor(s3, off, 64);
        }
        if (lane == 0) { s_red[0][wv] = s1; s_red[1][wv] = s2; s_red[2][wv] = s3; }
        __syncthreads();
        if (tid == 0) {
            atomicAdd(&accum[0], (double)(s_red[0][0] + s_red[0][1] + s_red[0][2] + s_red[0][3]));
            atomicAdd(&accum[1], (double)(s_red[1][0] + s_red[1][1] + s_red[1][2] + s_red[1][3]));
            atomicAdd(&accum[2], (double)(s_red[2][0] + s_red[2][1] + s_red[2][2] + s_red[2][3]));
        }
    } else {
        // ---- role B: lane = truth (2/lane), wave-uniform prior broadcast.
        {
            int p = base + tid;
            float2 c = ((const float2*)locs)[p];
            float w = params[3 * p];
            float h = params[3 * p + 1];
            s_p[tid] = make_float4(c.x - 0.5f * w, c.y - 0.5f * h,
                                   c.x + 0.5f * w, c.y + 0.5f * h);
        }
        float4 t0 = ((const float4*)truths)[lane];
        float4 t1 = ((const float4*)truths)[64 + lane];
        float ta0 = (t0.z - t0.x) * (t0.w - t0.y);
        float ta1 = (t1.z - t1.x) * (t1.w - t1.y);
        __syncthreads();

        const int wbase = wv * 64;
        float maxv0 = -1.f, maxv1 = -1.f;
        unsigned int maxi0 = 0u, maxi1 = 0u;

#pragma unroll 4
        for (int j = 0; j < 64; ++j) {
            float4 pb = s_p[wbase + j];                // wave-uniform broadcast
            float parea = (pb.z - pb.x) * (pb.w - pb.y);
            unsigned int pg = (unsigned int)(base + wbase + j);
            {
                float lx = fmaxf(t0.x, pb.x);
                float ly = fmaxf(t0.y, pb.y);
                float rx = fminf(t0.z, pb.z);
                float ry = fminf(t0.w, pb.w);
                float w = fmaxf(rx - lx, 0.f);
                float h = fmaxf(ry - ly, 0.f);
                float inter = w * h;
                float iou = inter * __builtin_amdgcn_rcpf((ta0 + parea) - inter);
                if (iou > maxv0) { maxv0 = iou; maxi0 = pg; }  // strict >: first occ.
            }
            {
                float lx = fmaxf(t1.x, pb.x);
                float ly = fmaxf(t1.y, pb.y);
                float rx = fminf(t1.z, pb.z);
                float ry = fminf(t1.w, pb.w);
                float w = fmaxf(rx - lx, 0.f);
                float h = fmaxf(ry - ly, 0.f);
                float inter = w * h;
                float iou = inter * __builtin_amdgcn_rcpf((ta1 + parea) - inter);
                if (iou > maxv1) { maxv1 = iou; maxi1 = pg; }
            }
        }

        s_part[wv][lane] =
            ((unsigned long long)__float_as_uint(maxv0) << 32) |
            (unsigned long long)(~maxi0);
        s_part[wv][64 + lane] =
            ((unsigned long long)__float_as_uint(maxv1) << 32) |
            (unsigned long long)(~maxi1);
        __syncthreads();

        if (tid < T_CNT) {
            unsigned long long m = s_part[0][tid];
            unsigned long long x1 = s_part[1][tid];
            unsigned long long x2 = s_part[2][tid];
            unsigned long long x3 = s_part[3][tid];
            m = (x1 > m) ? x1 : m;
            m = (x2 > m) ? x2 : m;
            m = (x3 > m) ? x3 : m;
            atomicMax(&packed[tid], m);
        }
    }

    // ---- last-block ticket ----
    __threadfence();          // release this block's writes/atomics
    __syncthreads();
    if (tid == 0) s_ticket = atomicAdd(done, 1u);
    __syncthreads();
    if (s_ticket != NB_TOT - 1) return;

    // ---- finalize (runs in exactly one block, after all others) ----
    __threadfence();          // acquire
    unsigned long long v = 0ull;
    float ov = 0.f;
    unsigned int pi = 0u;
    if (tid < T_CNT) {
        v = packed[tid];
        ov = __uint_as_float((unsigned int)(v >> 32));     // best_prior_overlap[t]
        pi = ~(unsigned int)(v & 0xFFFFFFFFull);           // best_prior_idx[t]
        s_idx[tid] = pi;
    }
    __syncthreads();

    float c2 = 0.f, c3 = 0.f;
    if (tid < T_CNT) {
        // numpy fancy-assignment: duplicate indices -> last t wins
        bool is_last = true;
        for (int u = tid + 1; u < T_CNT; ++u)
            if (s_idx[u] == pi) is_last = false;
        if (is_last && v != 0ull) {
            float old = bto[pi];
            float oxf = (old > IOU_TH) ? 1.f : 0.f;
            float a = params[3 * pi + 2];
            float sig = 1.f / (1.f + expf(-a));
            float oldterm = (oxf > 0.f) ? sig * logf(old) : 0.f;
            float newterm = K_CONST * sig * logf(ov);
            c3 = newterm - oldterm;
            c2 = K_CONST - oxf;
        }
    }
#pragma unroll
    for (int off = 32; off; off >>= 1) {
        c2 += __shfl_xor(c2, off, 64);
        c3 += __shfl_xor(c3, off, 64);
    }
    if (lane == 0) { s_sw[wv * 2] = c2; s_sw[wv * 2 + 1] = c3; }
    __syncthreads();

    if (tid == 0) {
        double S1 = accum[0];
        double S2 = accum[1] + (double)(s_sw[0] + s_sw[2]);  // waves 2,3 contribute 0
        double S3 = accum[2] + (double)(s_sw[1] + s_sw[3]);
        out[0] = (float)((S1 - S3) / S2);  // BETA = 1.0
    }
}

extern "C" void kernel_launch(void* const* d_in, const int* in_sizes, int n_in,
                              void* d_out, int out_size, void* d_ws, size_t ws_size,
                              hipStream_t stream) {
    const float* locs   = (const float*)d_in[0];
    const float* params = (const float*)d_in[1];
    const float* truths = (const float*)d_in[2];

    double* accum = (double*)((char*)d_ws + WS_ACC_OFF);
    unsigned long long* packed = (unsigned long long*)((char*)d_ws + WS_PACKED_OFF);
    unsigned int* done = (unsigned int*)((char*)d_ws + WS_DONE_OFF);
    float* bto = (float*)((char*)d_ws + WS_BTO_OFF);

    // ws is poisoned 0xAA and never re-poisoned: zero accum+packed+done each call
    (void)hipMemsetAsync(d_ws, 0, 2048, stream);

    apb_work<<<NB_TOT, 256, 0, stream>>>(locs, params, truths, bto, packed,
                                         accum, done, (float*)d_out);
}

// Round 9
// 63.548 us; speedup vs baseline: 2.2818x; 2.2818x over previous
//
#include <hip/hip_runtime.h>

#define T_CNT   128
#define IOU_TH  0.4f
#define K_CONST 2.5f
#define PPB     256    // priors per block (64 per wave)
#define QP      16     // priors per quarter-phase (per-wave bto reduce)

// ws layout:
//   [0,32)        double accum[3]: S1=sum(sig), S2=sum(xf), S3=sum(sig*xf*log(bto))
//   [64,1088)     unsigned long long packed[128]: (iou_bits<<32) | ~prior_idx
//   [4096, +P*4)  float bto[P]
static const size_t WS_ACC_OFF    = 0;
static const size_t WS_PACKED_OFF = 64;
static const size_t WS_BTO_OFF    = 4096;

// Single pass over the IoU matrix. Per block: 256 priors, 4 waves, each wave
// owns 64 priors x all 128 truths (2 truths/lane, wave-uniform prior
// broadcast). Per-truth argmax: register-resident, no cross-lane in loop.
// Per-prior max: per-lane pair-max staged to LDS (1 ds_write/iter), reduced
// wave-locally in 4 quarter phases (no barriers, no DPP chains).
__global__ __launch_bounds__(256) void apb_fused(
    const float* __restrict__ locs, const float* __restrict__ params,
    const float* __restrict__ truths, float* __restrict__ bto,
    unsigned long long* __restrict__ packed, double* __restrict__ accum)
{
    __shared__ float4 s_p[PPB];                       // 4 KB
    __shared__ float  s_m[4][QP][64];                 // 16 KB, per-wave slices
    __shared__ unsigned long long s_part[4][T_CNT];   // 4 KB
    __shared__ float s_red[3][4];

    const int tid  = threadIdx.x;
    const int lane = tid & 63;
    const int wv   = tid >> 6;
    const int base = blockIdx.x * PPB;

    // stage this block's 256 priors (corner form)
    {
        int p = base + tid;
        float2 c = ((const float2*)locs)[p];
        float w = params[3 * p];
        float h = params[3 * p + 1];
        s_p[tid] = make_float4(c.x - 0.5f * w, c.y - 0.5f * h,
                               c.x + 0.5f * w, c.y + 0.5f * h);
    }
    // per-lane truths (2 each)
    float4 t0 = ((const float4*)truths)[lane];
    float4 t1 = ((const float4*)truths)[64 + lane];
    float ta0 = (t0.z - t0.x) * (t0.w - t0.y);
    float ta1 = (t1.z - t1.x) * (t1.w - t1.y);
    __syncthreads();

    const int wbase = wv * 64;
    float maxv0 = -1.f, maxv1 = -1.f;
    unsigned int maxi0 = 0u, maxi1 = 0u;
    float btsel = 0.f;                 // lane ends up owning prior wbase+lane
    const int j0  = lane & 15;
    const int seg = lane >> 4;         // 0..3

    for (int qtr = 0; qtr < 4; ++qtr) {
#pragma unroll
        for (int jj = 0; jj < QP; ++jj) {
            const int j = qtr * QP + jj;
            float4 pb = s_p[wbase + j];                 // wave-uniform broadcast
            float parea = (pb.z - pb.x) * (pb.w - pb.y);
            unsigned int pg = (unsigned int)(base + wbase + j);

            float iou0, iou1;
            {
                float lx = fmaxf(t0.x, pb.x);
                float ly = fmaxf(t0.y, pb.y);
                float rx = fminf(t0.z, pb.z);
                float ry = fminf(t0.w, pb.w);
                float w = fmaxf(rx - lx, 0.f);
                float h = fmaxf(ry - ly, 0.f);
                float inter = w * h;
                iou0 = inter * __builtin_amdgcn_rcpf((ta0 + parea) - inter);
            }
            {
                float lx = fmaxf(t1.x, pb.x);
                float ly = fmaxf(t1.y, pb.y);
                float rx = fminf(t1.z, pb.z);
                float ry = fminf(t1.w, pb.w);
                float w = fmaxf(rx - lx, 0.f);
                float h = fmaxf(ry - ly, 0.f);
                float inter = w * h;
                iou1 = inter * __builtin_amdgcn_rcpf((ta1 + parea) - inter);
            }
            // per-truth running argmax (strict >, pg increasing -> first occ.)
            if (iou0 > maxv0) { maxv0 = iou0; maxi0 = pg; }
            if (iou1 > maxv1) { maxv1 = iou1; maxi1 = pg; }
            // per-prior partial: this lane's max over its 2 truths
            s_m[wv][jj][lane] = fmaxf(iou0, iou1);
        }
        // wave-local per-prior reduce for this quarter's 16 priors.
        // lane (seg,j0) serially maxes s_m[wv][j0][seg*16 + (k+j0)&15]
        // (rotation spreads banks; 2-way residual aliasing is free).
        // Same-wave DS ordering makes the jj-loop writes visible; no barrier.
        float m = -1.f;
#pragma unroll
        for (int k = 0; k < QP; ++k) {
            int kk = (k + j0) & 15;
            m = fmaxf(m, s_m[wv][j0][seg * 16 + kk]);
        }
        m = fmaxf(m, __shfl_xor(m, 16, 64));
        m = fmaxf(m, __shfl_xor(m, 32, 64));
        if (seg == qtr) btsel = m;     // prior wbase + qtr*16 + j0 == wbase+lane
    }

    // ---- epilogue ----
    // per-truth argmax partials -> LDS -> 4-way fold -> one atomic per truth
    s_part[wv][lane] =
        ((unsigned long long)__float_as_uint(maxv0) << 32) |
        (unsigned long long)(~maxi0);
    s_part[wv][64 + lane] =
        ((unsigned long long)__float_as_uint(maxv1) << 32) |
        (unsigned long long)(~maxi1);

    // per-prior outputs: lane owns prior q = base + wbase + lane
    const int q = base + wbase + lane;
    bto[q] = btsel;
    float a = params[3 * q + 2];
    float sig = 1.f / (1.f + expf(-a));
    float xf = (btsel > IOU_TH) ? 1.f : 0.f;
    float s1 = sig;
    float s2 = xf;
    float s3 = (xf > 0.f) ? sig * logf(btsel) : 0.f;
#pragma unroll
    for (int off = 32; off; off >>= 1) {
        s1 += __shfl_xor(s1, off, 64);
        s2 += __shfl_xor(s2, off, 64);
        s3 += __shfl_xor(s3, off, 64);
    }
    if (lane == 0) { s_red[0][wv] = s1; s_red[1][wv] = s2; s_red[2][wv] = s3; }
    __syncthreads();

    if (tid < T_CNT) {
        unsigned long long m = s_part[0][tid];
        unsigned long long x1 = s_part[1][tid];
        unsigned long long x2 = s_part[2][tid];
        unsigned long long x3 = s_part[3][tid];
        m = (x1 > m) ? x1 : m;
        m = (x2 > m) ? x2 : m;
        m = (x3 > m) ? x3 : m;
        atomicMax(&packed[tid], m);
    }
    if (tid == 0) {
        atomicAdd(&accum[0], (double)(s_red[0][0] + s_red[0][1] + s_red[0][2] + s_red[0][3]));
        atomicAdd(&accum[1], (double)(s_red[1][0] + s_red[1][1] + s_red[1][2] + s_red[1][3]));
        atomicAdd(&accum[2], (double)(s_red[2][0] + s_red[2][1] + s_red[2][2] + s_red[2][3]));
    }
}

// ---------------- Finalize: scatter corrections + scalar loss --------------
__global__ __launch_bounds__(128) void apb_final(
    const float* __restrict__ params, const float* __restrict__ bto,
    const unsigned long long* __restrict__ packed,
    const double* __restrict__ accum, float* __restrict__ out)
{
    const int t = threadIdx.x;
    __shared__ unsigned int s_idx[T_CNT];

    unsigned long long v = packed[t];
    float ov = __uint_as_float((unsigned int)(v >> 32));     // best_prior_overlap[t]
    unsigned int p = ~(unsigned int)(v & 0xFFFFFFFFull);     // best_prior_idx[t]
    s_idx[t] = p;
    __syncthreads();

    // numpy fancy-assignment semantics: duplicate indices -> last t wins
    bool is_last = true;
    for (int u = t + 1; u < T_CNT; ++u)
        if (s_idx[u] == p) is_last = false;

    float c2 = 0.f, c3 = 0.f;
    if (is_last && v != 0ull) {
        float old = bto[p];
        float oxf = (old > IOU_TH) ? 1.f : 0.f;
        float a = params[3 * p + 2];
        float sig = 1.f / (1.f + expf(-a));
        float oldterm = (oxf > 0.f) ? sig * logf(old) : 0.f;
        float newterm = K_CONST * sig * logf(ov);
        c3 = newterm - oldterm;
        c2 = K_CONST - oxf;
    }

#pragma unroll
    for (int off = 32; off; off >>= 1) {
        c2 += __shfl_xor(c2, off, 64);
        c3 += __shfl_xor(c3, off, 64);
    }
    __shared__ float sw[4];
    if ((t & 63) == 0) { sw[(t >> 6) * 2] = c2; sw[(t >> 6) * 2 + 1] = c3; }
    __syncthreads();

    if (t == 0) {
        double S1 = accum[0];
        double S2 = accum[1] + (double)(sw[0] + sw[2]);
        double S3 = accum[2] + (double)(sw[1] + sw[3]);
        out[0] = (float)((S1 - S3) / S2);  // BETA = 1.0
    }
}

extern "C" void kernel_launch(void* const* d_in, const int* in_sizes, int n_in,
                              void* d_out, int out_size, void* d_ws, size_t ws_size,
                              hipStream_t stream) {
    const float* locs   = (const float*)d_in[0];
    const float* params = (const float*)d_in[1];
    const float* truths = (const float*)d_in[2];
    const int P = in_sizes[0] / 2;  // 262144

    double* accum = (double*)((char*)d_ws + WS_ACC_OFF);
    unsigned long long* packed = (unsigned long long*)((char*)d_ws + WS_PACKED_OFF);
    float* bto = (float*)((char*)d_ws + WS_BTO_OFF);

    // ws is poisoned 0xAA and never re-poisoned: zero accum + packed each call
    (void)hipMemsetAsync(d_ws, 0, 1088, stream);

    apb_fused<<<P / PPB, 256, 0, stream>>>(locs, params, truths, bto, packed, accum);
    apb_final<<<1, 128, 0, stream>>>(params, bto, packed, accum, (float*)d_out);
}